// Round 1
// baseline (151.786 us; speedup 1.0000x reference)
//
#include <hip/hip_runtime.h>
#include <float.h>
#include <math.h>

#define NEG 0.2f

// ---------------- CSR build ----------------
__global__ void k_init_deg(int* deg, int n) {
  int i = blockIdx.x * blockDim.x + threadIdx.x;
  if (i < n) deg[i] = 1;  // self-loop
}

__global__ void k_count(const int* __restrict__ ei, int E, int* deg) {
  int e = blockIdx.x * blockDim.x + threadIdx.x;
  if (e < E) atomicAdd(&deg[ei[E + e]], 1);
}

__global__ __launch_bounds__(1024) void k_scan(const int* __restrict__ deg,
                                               int* offs, int* cursor, int n) {
  __shared__ int lds[1024];
  __shared__ int carry_s;
  if (threadIdx.x == 0) carry_s = 0;
  __syncthreads();
  for (int base = 0; base < n; base += 1024) {
    int i = base + (int)threadIdx.x;
    int v = (i < n) ? deg[i] : 0;
    lds[threadIdx.x] = v;
    __syncthreads();
    for (int off = 1; off < 1024; off <<= 1) {
      int t = (threadIdx.x >= (unsigned)off) ? lds[threadIdx.x - off] : 0;
      __syncthreads();
      lds[threadIdx.x] += t;
      __syncthreads();
    }
    int carry = carry_s;
    int excl = carry + lds[threadIdx.x] - v;
    if (i < n) { offs[i] = excl; cursor[i] = excl; }
    __syncthreads();
    if (threadIdx.x == 0) carry_s = carry + lds[1023];
    __syncthreads();
  }
}

__global__ void k_scatter(const int* __restrict__ ei, int E, int N,
                          int* cursor, int* edge_src) {
  int t = blockIdx.x * blockDim.x + threadIdx.x;
  if (t < E) {
    int s = ei[t], d = ei[E + t];
    int pos = atomicAdd(&cursor[d], 1);
    edge_src[pos] = s;
  } else if (t < E + N) {
    int nn = t - E;
    int pos = atomicAdd(&cursor[nn], 1);
    edge_src[pos] = nn;
  }
}

// ---------------- layer-1 GEMM (h1 = x @ W1^T) + fused attention logits ----------------
// grid: (ceil(N/64), 8 heads); block 256.  col-tile == head (64 cols).
__global__ __launch_bounds__(256) void k_gemm1(
    const float* __restrict__ x, const float* __restrict__ W1,
    const float* __restrict__ a_s, const float* __restrict__ a_d,
    float* __restrict__ h1, float* __restrict__ as1, float* __restrict__ ad1, int N) {
  __shared__ float xs[64 * 129];
  __shared__ float wsl[64 * 129];
  int node0 = blockIdx.x * 64;
  int h = blockIdx.y;
  int col0 = h * 64;
  int tid = threadIdx.x;
  int nvalid = min(64, N - node0);

  const float4* x4 = (const float4*)x;
  const float4* w4 = (const float4*)W1;
#pragma unroll
  for (int i = 0; i < 8; i++) {
    int idx = tid + i * 256;          // float4 index within 64x128 tile
    int row = idx >> 5, kq = idx & 31;
    float4 v = make_float4(0.f, 0.f, 0.f, 0.f);
    if (row < nvalid) v = x4[(size_t)(node0 + row) * 32 + kq];
    float* p = &xs[row * 129 + kq * 4];
    p[0] = v.x; p[1] = v.y; p[2] = v.z; p[3] = v.w;
  }
#pragma unroll
  for (int i = 0; i < 8; i++) {
    int idx = tid + i * 256;
    int row = idx >> 5, kq = idx & 31;
    float4 v = w4[(size_t)(col0 + row) * 32 + kq];
    float* p = &wsl[row * 129 + kq * 4];
    p[0] = v.x; p[1] = v.y; p[2] = v.z; p[3] = v.w;
  }
  __syncthreads();

  int tx = tid & 15, ty = tid >> 4;
  float acc[4][4] = {};
  for (int k = 0; k < 128; k++) {
    float a[4], b[4];
#pragma unroll
    for (int i = 0; i < 4; i++) a[i] = xs[(ty * 4 + i) * 129 + k];
#pragma unroll
    for (int j = 0; j < 4; j++) b[j] = wsl[(tx * 4 + j) * 129 + k];
#pragma unroll
    for (int i = 0; i < 4; i++)
#pragma unroll
      for (int j = 0; j < 4; j++) acc[i][j] = fmaf(a[i], b[j], acc[i][j]);
  }

#pragma unroll
  for (int i = 0; i < 4; i++) {
    int node = node0 + ty * 4 + i;
    if (node < N) {
      float4 v = make_float4(acc[i][0], acc[i][1], acc[i][2], acc[i][3]);
      *(float4*)&h1[(size_t)node * 512 + col0 + tx * 4] = v;
    }
  }
  // fused: alpha_s[node][h] = sum_d h1[node][h*64+d]*a_s[h][d]  (d = tx*4+j)
  float ps[4], pd[4];
#pragma unroll
  for (int i = 0; i < 4; i++) {
    float s = 0.f, d = 0.f;
#pragma unroll
    for (int j = 0; j < 4; j++) {
      float av = a_s[h * 64 + tx * 4 + j];
      float dv = a_d[h * 64 + tx * 4 + j];
      s = fmaf(acc[i][j], av, s);
      d = fmaf(acc[i][j], dv, d);
    }
    ps[i] = s; pd[i] = d;
  }
#pragma unroll
  for (int o = 8; o >= 1; o >>= 1) {
#pragma unroll
    for (int i = 0; i < 4; i++) {
      ps[i] += __shfl_xor(ps[i], o);
      pd[i] += __shfl_xor(pd[i], o);
    }
  }
  if (tx == 0) {
#pragma unroll
    for (int i = 0; i < 4; i++) {
      int node = node0 + ty * 4 + i;
      if (node < N) { as1[node * 8 + h] = ps[i]; ad1[node * 8 + h] = pd[i]; }
    }
  }
}

// ---------------- layer-1 aggregation (online softmax) + fused layer-2 linear ----------------
// one block (256 thr) per destination node; each thread owns 2 of 512 channels.
__global__ __launch_bounds__(256) void k_gat1(
    const float* __restrict__ h1, const float* __restrict__ as1, const float* __restrict__ ad1,
    const int* __restrict__ offs, const int* __restrict__ degs, const int* __restrict__ edge_src,
    const float* __restrict__ b1, const float* __restrict__ W2,
    const float* __restrict__ a_s2, const float* __restrict__ a_d2,
    float* __restrict__ h2, float* __restrict__ as2, float* __restrict__ ad2, int N) {
  const int CAP = 128;
  __shared__ int src_lds[CAP];
  __shared__ float e_lds[CAP * 8];
  __shared__ float red[256];
  __shared__ float adn[8], mrun[8], drun[8], scl[8];
  __shared__ float2 rbuf[256];

  int n = blockIdx.x;
  int tid = threadIdx.x;
  int start = offs[n], dg = degs[n];
  if (tid < 8) { adn[tid] = ad1[n * 8 + tid]; mrun[tid] = -FLT_MAX; drun[tid] = 0.f; }
  __syncthreads();

  float acc0 = 0.f, acc1 = 0.f;
  int c0 = tid * 2;
  int ht = tid >> 5;  // head of owned channels

  for (int base = 0; base < dg; base += CAP) {
    int cnt = min(CAP, dg - base);
    for (int j = tid; j < cnt; j += 256) src_lds[j] = edge_src[start + base + j];
    __syncthreads();
    for (int t = tid; t < cnt * 8; t += 256) {
      int j = t >> 3, h = t & 7;
      int s = src_lds[j];
      float v = as1[s * 8 + h] + adn[h];
      e_lds[t] = v > 0.f ? v : NEG * v;
    }
    __syncthreads();
    {  // chunk max per head
      int g = tid >> 3, h = tid & 7;
      float p = -FLT_MAX;
      for (int j = g; j < cnt; j += 32) p = fmaxf(p, e_lds[j * 8 + h]);
      red[tid] = p;
    }
    __syncthreads();
    for (int s = 128; s >= 8; s >>= 1) {
      if (tid < s) red[tid] = fmaxf(red[tid], red[tid + s]);
      __syncthreads();
    }
    if (tid < 8) {
      float mn = fmaxf(mrun[tid], red[tid]);
      scl[tid] = expf(mrun[tid] - mn);
      mrun[tid] = mn;
    }
    __syncthreads();
    float sc = scl[ht];
    acc0 *= sc; acc1 *= sc;
    for (int t = tid; t < cnt * 8; t += 256) {
      int h = t & 7;
      e_lds[t] = expf(e_lds[t] - mrun[h]);
    }
    __syncthreads();
    {  // chunk sum per head
      int g = tid >> 3, h = tid & 7;
      float p = 0.f;
      for (int j = g; j < cnt; j += 32) p += e_lds[j * 8 + h];
      red[tid] = p;
    }
    __syncthreads();
    for (int s = 128; s >= 8; s >>= 1) {
      if (tid < s) red[tid] += red[tid + s];
      __syncthreads();
    }
    if (tid < 8) drun[tid] = drun[tid] * scl[tid] + red[tid];
    // aggregate messages
    const float2* h1f2 = (const float2*)h1;
    for (int j = 0; j < cnt; j++) {
      float w = e_lds[j * 8 + ht];
      float2 v = h1f2[(size_t)src_lds[j] * 256 + tid];
      acc0 = fmaf(w, v.x, acc0);
      acc1 = fmaf(w, v.y, acc1);
    }
    __syncthreads();
  }

  float dn = drun[ht] + 1e-16f;
  float v0 = acc0 / dn + b1[c0];
  float v1 = acc1 / dn + b1[c0 + 1];
  v0 = v0 > 0.f ? v0 : expm1f(v0);  // ELU
  v1 = v1 > 0.f ? v1 : expm1f(v1);
  // fused layer-2 linear: h2 = elu_out1 @ W2^T   (W2: [2][512])
  float p0 = v0 * W2[c0] + v1 * W2[c0 + 1];
  float p1 = v0 * W2[512 + c0] + v1 * W2[512 + c0 + 1];
  rbuf[tid] = make_float2(p0, p1);
  __syncthreads();
  for (int s = 128; s >= 1; s >>= 1) {
    if (tid < s) { float2 o = rbuf[tid + s]; rbuf[tid].x += o.x; rbuf[tid].y += o.y; }
    __syncthreads();
  }
  if (tid == 0) {
    float hx = rbuf[0].x, hy = rbuf[0].y;
    ((float2*)h2)[n] = make_float2(hx, hy);
    as2[n] = hx * a_s2[0] + hy * a_s2[1];
    ad2[n] = hx * a_d2[0] + hy * a_d2[1];
  }
}

// ---------------- layer-2 aggregation: one wave per node ----------------
__global__ __launch_bounds__(64) void k_gat2(
    const float* __restrict__ h2, const float* __restrict__ as2, const float* __restrict__ ad2,
    const int* __restrict__ offs, const int* __restrict__ degs, const int* __restrict__ edge_src,
    const float* __restrict__ b2, float* __restrict__ out, int N) {
  int n = blockIdx.x;
  int lane = threadIdx.x;
  int start = offs[n], dg = degs[n];
  float adn = ad2[n];
  float m = -FLT_MAX;
  for (int j = lane; j < dg; j += 64) {
    int s = edge_src[start + j];
    float v = as2[s] + adn;
    v = v > 0.f ? v : NEG * v;
    m = fmaxf(m, v);
  }
#pragma unroll
  for (int o = 32; o >= 1; o >>= 1) m = fmaxf(m, __shfl_xor(m, o));
  float den = 0.f, n0 = 0.f, n1 = 0.f;
  const float2* h2f = (const float2*)h2;
  for (int j = lane; j < dg; j += 64) {
    int s = edge_src[start + j];
    float v = as2[s] + adn;
    v = v > 0.f ? v : NEG * v;
    float w = expf(v - m);
    float2 hv = h2f[s];
    den += w;
    n0 = fmaf(w, hv.x, n0);
    n1 = fmaf(w, hv.y, n1);
  }
#pragma unroll
  for (int o = 32; o >= 1; o >>= 1) {
    den += __shfl_xor(den, o);
    n0 += __shfl_xor(n0, o);
    n1 += __shfl_xor(n1, o);
  }
  if (lane == 0) {
    out[n * 2 + 0] = n0 / (den + 1e-16f) + b2[0];
    out[n * 2 + 1] = n1 / (den + 1e-16f) + b2[1];
  }
}

extern "C" void kernel_launch(void* const* d_in, const int* in_sizes, int n_in,
                              void* d_out, int out_size, void* d_ws, size_t ws_size,
                              hipStream_t stream) {
  const float* x    = (const float*)d_in[0];
  const int*   ei   = (const int*)d_in[1];
  const float* W1   = (const float*)d_in[2];
  const float* a_s1 = (const float*)d_in[3];
  const float* a_d1 = (const float*)d_in[4];
  const float* b1   = (const float*)d_in[5];
  const float* W2   = (const float*)d_in[6];
  const float* a_s2 = (const float*)d_in[7];
  const float* a_d2 = (const float*)d_in[8];
  const float* b2   = (const float*)d_in[9];
  int N = in_sizes[0] / 128;
  int E = in_sizes[1] / 2;

  float* ws  = (float*)d_ws;
  float* h1  = ws;                              // N*512
  float* as1 = h1 + (size_t)N * 512;            // N*8
  float* ad1 = as1 + (size_t)N * 8;             // N*8
  float* h2  = ad1 + (size_t)N * 8;             // N*2
  float* as2 = h2 + (size_t)N * 2;              // N
  float* ad2 = as2 + N;                         // N
  int* deg      = (int*)(ad2 + N);              // N
  int* offs     = deg + N;                      // N
  int* cursor   = offs + N;                     // N
  int* edge_src = cursor + N;                   // E+N

  k_init_deg<<<(N + 255) / 256, 256, 0, stream>>>(deg, N);
  k_count<<<(E + 255) / 256, 256, 0, stream>>>(ei, E, deg);
  k_scan<<<1, 1024, 0, stream>>>(deg, offs, cursor, N);
  k_scatter<<<(E + N + 255) / 256, 256, 0, stream>>>(ei, E, N, cursor, edge_src);
  dim3 g1((N + 63) / 64, 8);
  k_gemm1<<<g1, 256, 0, stream>>>(x, W1, a_s1, a_d1, h1, as1, ad1, N);
  k_gat1<<<N, 256, 0, stream>>>(h1, as1, ad1, offs, deg, edge_src, b1, W2, a_s2, a_d2,
                                h2, as2, ad2, N);
  k_gat2<<<N, 64, 0, stream>>>(h2, as2, ad2, offs, deg, edge_src, b2, (float*)d_out, N);
}